// Round 3
// baseline (473.226 us; speedup 1.0000x reference)
//
#include <hip/hip_runtime.h>

// Problem constants (fixed by setup_inputs in the reference):
//   k,v: [B=2, C=128, Hc=48, Wc=48] fp32; NUM_HEADS=8 -> hd=16
//   WINDOW=5, DILATION=1 -> K=25 offsets, r=2
//   query grid 96x96, scale_factor=2
// Outputs (flat, concatenated):
//   out0 k_nb  [2,8,25,16,96,96]  = 58,982,400 floats
//   out1 v_nb  [2,8,25,16,96,96]  = 58,982,400 floats
//   out2 mask  [2,8,25,96,96]     =  3,686,400 floats (bool -> 0.0/1.0)

#define KV_ELEMS  58982400LL
#define MASK_OFF  117964800LL

typedef float f32x4 __attribute__((ext_vector_type(4)));

// 4 d-planes per thread. grid = (36, 25, 16): y=kk, z=b*8+h.
// t2 = blockIdx.x*256+tx in [0,9216) = d0*2304 + y*24 + x4, d0 in 0..3.
// Thread handles d = d0+4u, u=0..3 (channel stride 2304 floats, out stride
// 9216 float4s) -> index math + validity computed ONCE for 4 units.
// Waves: 57,600 (was 230,400); stores remain 1024B-contiguous per wave
// (2304 % 64 == 0 so d0 boundaries align with wave boundaries).
__global__ __launch_bounds__(256) void fused_expand_kernel(
    const float* __restrict__ k, const float* __restrict__ v,
    float* __restrict__ out_k, float* __restrict__ out_v,
    float* __restrict__ out_m) {
    const int t2 = blockIdx.x * 256 + threadIdx.x;   // [0, 9216)
    const int kk = blockIdx.y;                        // 0..24
    const int z  = blockIdx.z;                        // b*8+h, 0..15

    const int q  = t2 / 24;              // = d0*96 + y
    const int x4 = t2 - q * 24;
    const int d0 = q / 96;               // 0..3
    const int y  = q - d0 * 96;

    // wave-uniform -> scalar unit
    const int kq = kk / 5;
    const int dy = kq - 2;
    const int dx = kk - kq * 5 - 2;

    const int yy  = (y >> 1) + dy;
    const bool vy = (unsigned)yy < 48u;
    const int xc0 = 2 * x4 + dx;
    const int xc1 = xc0 + 1;
    const bool v0 = vy && ((unsigned)xc0 < 48u);
    const bool v1 = vy && ((unsigned)xc1 < 48u);

    const int yc = vy ? yy : 0;
    const int x0 = min(max(xc0, 0), 47);
    const int x1 = min(max(xc1, 0), 47);

    // base for u=0; unit u adds 4*2304 = 9216 floats (d += 4)
    const int base0 = ((z * 16 + d0) * 48 + yc) * 48;

    // Issue all 16 loads branchlessly, then select.
    float kr0[4], kr1[4], vr0[4], vr1[4];
#pragma unroll
    for (int u = 0; u < 4; ++u) {
        const int base = base0 + u * 9216;
        kr0[u] = k[base + x0];
        kr1[u] = k[base + x1];
        vr0[u] = v[base + x0];
        vr1[u] = v[base + x1];
    }

    const int slice = z * 25 + kk;
    const int obase = slice * 36864 + t2;   // float4 index; +u*9216 per unit
#pragma unroll
    for (int u = 0; u < 4; ++u) {
        const float k0 = v0 ? kr0[u] : 0.0f;
        const float k1 = v1 ? kr1[u] : 0.0f;
        const float w0 = v0 ? vr0[u] : 0.0f;
        const float w1 = v1 ? vr1[u] : 0.0f;
        f32x4 ok = {k0, k0, k1, k1};
        f32x4 ov = {w0, w0, w1, w1};
        const int o = obase + u * 9216;
        __builtin_nontemporal_store(ok, reinterpret_cast<f32x4*>(out_k) + o);
        __builtin_nontemporal_store(ov, reinterpret_cast<f32x4*>(out_v) + o);
    }

    if (blockIdx.x < 9) {  // block-uniform: exactly the d0==0 blocks (t2 < 2304)
        const float m0 = v0 ? 1.0f : 0.0f;
        const float m1 = v1 ? 1.0f : 0.0f;
        f32x4 om = {m0, m0, m1, m1};
        __builtin_nontemporal_store(
            om, reinterpret_cast<f32x4*>(out_m) + slice * 2304 + t2);
    }
}

extern "C" void kernel_launch(void* const* d_in, const int* in_sizes, int n_in,
                              void* d_out, int out_size, void* d_ws, size_t ws_size,
                              hipStream_t stream) {
    const float* k = (const float*)d_in[0];
    const float* v = (const float*)d_in[1];
    float* out = (float*)d_out;
    float* out_k = out;
    float* out_v = out + KV_ELEMS;
    float* out_m = out + MASK_OFF;

    // 9216 threads per (kk,z) slice = 36 blocks x 256; grid (36, 25, 16)
    fused_expand_kernel<<<dim3(36, 25, 16), 256, 0, stream>>>(
        k, v, out_k, out_v, out_m);
}